// Round 2
// baseline (1812.084 us; speedup 1.0000x reference)
//
#include <hip/hip_runtime.h>
#include <hip/hip_bf16.h>
#include <cstdint>
#include <math.h>

using bf16 = __hip_bfloat16;

#define DEV __device__ __forceinline__

DEV float b2f(unsigned short u) { return __uint_as_float(((uint32_t)u) << 16); }
DEV float bf(const bf16 h) { return __bfloat162float(h); }

// flag: 1 = harness buffers are bf16, 0 = fp32.
DEV float ldv(const void* p, int isbf, size_t i) {
  return isbf ? bf(((const bf16*)p)[i]) : ((const float*)p)[i];
}

// load 8 consecutive weight elements (off multiple of 8) as fp32
DEV void ldw8(const void* w, int isbf, size_t off, float o[8]) {
  if (isbf) {
    uint4 q = *(const uint4*)((const bf16*)w + off);
    uint32_t s[4] = {q.x, q.y, q.z, q.w};
    #pragma unroll
    for (int j = 0; j < 4; ++j) {
      o[2 * j]     = __uint_as_float(s[j] << 16);
      o[2 * j + 1] = __uint_as_float(s[j] & 0xffff0000u);
    }
  } else {
    const float* f = (const float*)w + off;
    float4 a = *(const float4*)f;
    float4 b = *(const float4*)(f + 4);
    o[0] = a.x; o[1] = a.y; o[2] = a.z; o[3] = a.w;
    o[4] = b.x; o[5] = b.y; o[6] = b.z; o[7] = b.w;
  }
}

// ---------------------------------------------------------------------------
// dtype sniffer: sample x as u16 at even indices. bf16-packed normal data has
// sane exponent fields; fp32-packed data puts random mantissa bits there.
// ---------------------------------------------------------------------------
__global__ __launch_bounds__(256) void sniff_kernel(
    const unsigned short* __restrict__ xr, int* __restrict__ flag)
{
  int tid = threadIdx.x;
  int good = 0;
  for (int k = tid; k < 16384; k += 256) {
    unsigned short u = xr[2 * k];
    int e = (u >> 7) & 0xFF;
    good += (e >= 0x6A && e <= 0x86) ? 1 : 0;  // |v| in ~[2^-21, 2^7]
  }
  __shared__ int r[256];
  r[tid] = good;
  __syncthreads();
  for (int off = 128; off; off >>= 1) {
    if (tid < off) r[tid] += r[tid + off];
    __syncthreads();
  }
  if (tid == 0) *flag = (r[0] > 9830) ? 1 : 0;  // > 60% sane => bf16
}

// ---------------------------------------------------------------------------
// conv1x1: out[b][co][n] = sum_c w[co][c]*in[b][c][n] + bias[co]
// in: [B,K,4096] (flag dtype if DUALIN else bf16), w/bias: flag dtype,
// out: [B,CO,4096] bf16. Block 256, tile 64 n; wave owns CO/4 rows.
// ---------------------------------------------------------------------------
template<int K, int CO, bool DUALIN>
__global__ __launch_bounds__(256) void conv1x1_kernel(
    const void* __restrict__ in, const void* __restrict__ w,
    const void* __restrict__ bias, bf16* __restrict__ out,
    const int* __restrict__ flag)
{
  const int isbf = *flag;
  __shared__ bf16 xs[K][64];
  const int b = blockIdx.y;
  const int nbase = blockIdx.x * 64;
  const int tid = threadIdx.x;
  const size_t base = ((size_t)b * K) * 4096 + nbase;
  for (int i = 0; i < K / 4; ++i) {
    int idx = i * 256 + tid;
    int c = idx >> 6, nl = idx & 63;
    size_t o = base + (size_t)c * 4096 + nl;
    if (DUALIN && !isbf) xs[c][nl] = __float2bfloat16(((const float*)in)[o]);
    else                 xs[c][nl] = ((const bf16*)in)[o];
  }
  __syncthreads();
  const int lane = tid & 63;
  const int wv = __builtin_amdgcn_readfirstlane(tid >> 6);
  constexpr int R = CO / 4;
  const int r0 = wv * R;
  float acc[R];
  #pragma unroll
  for (int r = 0; r < R; ++r) acc[r] = 0.f;

  for (int c = 0; c < K; c += 8) {
    float xv[8];
    #pragma unroll
    for (int j = 0; j < 8; ++j) xv[j] = bf(xs[c + j][lane]);
    #pragma unroll
    for (int r = 0; r < R; ++r) {
      float wv8[8];
      ldw8(w, isbf, (size_t)(r0 + r) * K + c, wv8);
      #pragma unroll
      for (int j = 0; j < 8; ++j) acc[r] += wv8[j] * xv[j];
    }
  }
  bf16* op = out + ((size_t)b * CO) * 4096 + nbase + lane;
  #pragma unroll
  for (int r = 0; r < R; ++r)
    op[(size_t)(r0 + r) * 4096] = __float2bfloat16(acc[r] + ldv(bias, isbf, r0 + r));
}

// ---------------------------------------------------------------------------
// 2x2 maxpool on [b][c][64x64] bf16. phi keeps [b][ci][m]; g transposes to
// [b][m][ci].
// ---------------------------------------------------------------------------
__global__ __launch_bounds__(256) void pool_phi_kernel(
    const bf16* __restrict__ pc, bf16* __restrict__ phi)
{
  int idx = blockIdx.x * 256 + threadIdx.x;  // B*128*1024
  int m = idx & 1023, bc = idx >> 10;
  int mh = m >> 5, mw = m & 31;
  const bf16* p = pc + (size_t)bc * 4096 + mh * 128 + mw * 2;
  float v = fmaxf(fmaxf(bf(p[0]), bf(p[1])), fmaxf(bf(p[64]), bf(p[65])));
  phi[idx] = __float2bfloat16(v);
}

__global__ __launch_bounds__(256) void pool_g_kernel(
    const bf16* __restrict__ gc, bf16* __restrict__ g)
{
  int idx = blockIdx.x * 256 + threadIdx.x;  // B*1024*128
  int ci = idx & 127;
  int rest = idx >> 7;
  int m = rest & 1023, b = rest >> 10;
  int mh = m >> 5, mw = m & 31;
  const bf16* p = gc + ((size_t)(b * 128 + ci)) * 4096 + mh * 128 + mw * 2;
  float v = fmaxf(fmaxf(bf(p[0]), bf(p[1])), fmaxf(bf(p[64]), bf(p[65])));
  g[idx] = __float2bfloat16(v);
}

// ---------------------------------------------------------------------------
// Attention, direct exp (no online rescale; |scores| <~ 25, exp-safe in fp32).
// theta: [B,128,4096], phi: [B,128,1024], g: [B,1024,128], y: [B,128,4096].
// Block: (b, 64-n tile); 16 chunks of 64 m. in_=tid&15 (4 n), im=tid>>4.
// ---------------------------------------------------------------------------
__global__ __launch_bounds__(256) void attn_kernel(
    const bf16* __restrict__ theta, const bf16* __restrict__ phi,
    const bf16* __restrict__ g, bf16* __restrict__ y)
{
  __shared__ bf16 th[128][64];       // theta tile [ci][n]
  __shared__ bf16 bufh[128 * 64];    // phi [ci][64] then g [64][128]
  __shared__ float S[64][68];        // exp-scores [m][n], padded
  __shared__ float psum[16][64];
  __shared__ float lrun[64];

  const int b = blockIdx.y;
  const int nbase = blockIdx.x * 64;
  const int tid = threadIdx.x;
  const int in_ = tid & 15;
  const int im = tid >> 4;
  const int n0 = in_ * 4, m0 = im * 4, ci0 = im * 8;

  const bf16* tp = theta + ((size_t)b * 128) * 4096 + nbase;
  for (int i = 0; i < 32; ++i) {
    int idx = i * 256 + tid;
    int ci = idx >> 6, nl = idx & 63;
    th[ci][nl] = tp[(size_t)ci * 4096 + nl];
  }
  if (tid < 64) lrun[tid] = 0.f;

  float yacc[4][8];
  #pragma unroll
  for (int j = 0; j < 4; ++j)
    #pragma unroll
    for (int k = 0; k < 8; ++k) yacc[j][k] = 0.f;

  const bf16* pp = phi + ((size_t)b * 128) * 1024;
  const bf16* gp = g + ((size_t)b * 1024) * 128;

  for (int mc = 0; mc < 16; ++mc) {
    __syncthreads();  // (A) th ready / prev chunk's S,bufh consumed
    for (int i = 0; i < 32; ++i) {
      int idx = i * 256 + tid;
      int ci = idx >> 6, ml = idx & 63;
      bufh[ci * 64 + ml] = pp[((size_t)ci << 10) + (mc * 64 + ml)];
    }
    __syncthreads();  // (B) phi chunk ready

    float s[4][4];
    #pragma unroll
    for (int i = 0; i < 4; ++i)
      #pragma unroll
      for (int j = 0; j < 4; ++j) s[i][j] = 0.f;
    #pragma unroll 4
    for (int ci = 0; ci < 128; ++ci) {
      ushort4 tu = *(const ushort4*)&th[ci][n0];
      ushort4 pu = *(const ushort4*)&bufh[ci * 64 + m0];
      float a[4] = {b2f(tu.x), b2f(tu.y), b2f(tu.z), b2f(tu.w)};
      float p[4] = {b2f(pu.x), b2f(pu.y), b2f(pu.z), b2f(pu.w)};
      #pragma unroll
      for (int i = 0; i < 4; ++i)
        #pragma unroll
        for (int j = 0; j < 4; ++j) s[i][j] += p[i] * a[j];
    }

    float P[4][4];
    float ps[4] = {0.f, 0.f, 0.f, 0.f};
    #pragma unroll
    for (int i = 0; i < 4; ++i)
      #pragma unroll
      for (int j = 0; j < 4; ++j) {
        P[i][j] = __expf(fminf(s[i][j], 80.f));
        ps[j] += P[i][j];
      }
    #pragma unroll
    for (int i = 0; i < 4; ++i)
      *(float4*)&S[m0 + i][n0] = make_float4(P[i][0], P[i][1], P[i][2], P[i][3]);
    #pragma unroll
    for (int j = 0; j < 4; ++j) psum[im][n0 + j] = ps[j];
    __syncthreads();  // (C) S, psum ready; bufh(phi) consumed

    if (tid < 64) {
      float t = 0.f;
      #pragma unroll
      for (int k = 0; k < 16; ++k) t += psum[k][tid];
      lrun[tid] += t;
    }
    for (int i = 0; i < 32; ++i) {
      int idx = i * 256 + tid;
      int ml = idx >> 7, cc = idx & 127;
      bufh[ml * 128 + cc] = gp[(size_t)(mc * 64 + ml) * 128 + cc];
    }
    __syncthreads();  // (D) g chunk ready

    for (int ml = 0; ml < 64; ++ml) {
      float4 pv = *(const float4*)&S[ml][n0];
      ushort4 g0 = *(const ushort4*)&bufh[ml * 128 + ci0];
      ushort4 g1 = *(const ushort4*)&bufh[ml * 128 + ci0 + 4];
      float gv[8] = {b2f(g0.x), b2f(g0.y), b2f(g0.z), b2f(g0.w),
                     b2f(g1.x), b2f(g1.y), b2f(g1.z), b2f(g1.w)};
      float pj[4] = {pv.x, pv.y, pv.z, pv.w};
      #pragma unroll
      for (int j = 0; j < 4; ++j)
        #pragma unroll
        for (int k = 0; k < 8; ++k) yacc[j][k] += pj[j] * gv[k];
    }
  }
  __syncthreads();

  float li[4];
  #pragma unroll
  for (int j = 0; j < 4; ++j) li[j] = 1.0f / lrun[n0 + j];
  #pragma unroll
  for (int j = 0; j < 4; ++j)
    #pragma unroll
    for (int k = 0; k < 8; ++k)
      th[ci0 + k][n0 + j] = __float2bfloat16(yacc[j][k] * li[j]);
  __syncthreads();
  bf16* yp = y + ((size_t)b * 128) * 4096 + nbase;
  for (int i = 0; i < 32; ++i) {
    int idx = i * 256 + tid;
    int ci = idx >> 6, nl = idx & 63;
    yp[(size_t)ci * 4096 + nl] = th[ci][nl];
  }
}

// ---------------------------------------------------------------------------
// BatchNorm stats (one block per channel) + apply w/ residual.
// ---------------------------------------------------------------------------
__global__ __launch_bounds__(256) void bn_stats_kernel(
    const bf16* __restrict__ Wy, const void* __restrict__ gamma,
    const void* __restrict__ beta, float* __restrict__ stats,
    const int* __restrict__ flag)
{
  const int isbf = *flag;
  const int c = blockIdx.x;
  const int tid = threadIdx.x;
  float s = 0.f, s2 = 0.f;
  for (int b = 0; b < 8; ++b) {
    const bf16* p = Wy + ((size_t)(b * 256 + c)) * 4096;
    for (int i = tid; i < 4096; i += 256) {
      float v = bf(p[i]);
      s += v; s2 += v * v;
    }
  }
  __shared__ float rs[256], rs2[256];
  rs[tid] = s; rs2[tid] = s2;
  __syncthreads();
  for (int off = 128; off > 0; off >>= 1) {
    if (tid < off) { rs[tid] += rs[tid + off]; rs2[tid] += rs2[tid + off]; }
    __syncthreads();
  }
  if (tid == 0) {
    float mean = rs[0] * (1.0f / 32768.0f);
    float var = rs2[0] * (1.0f / 32768.0f) - mean * mean;
    var = fmaxf(var, 0.f);
    float rstd = rsqrtf(var + 1e-5f);
    float scale = rstd * ldv(gamma, isbf, c);
    stats[c] = scale;
    stats[256 + c] = ldv(beta, isbf, c) - mean * scale;
  }
}

__global__ __launch_bounds__(256) void bn_apply_kernel(
    const bf16* __restrict__ Wy, const void* __restrict__ x,
    const float* __restrict__ stats, void* __restrict__ out,
    const int* __restrict__ flag)
{
  const int isbf = *flag;
  int idx = blockIdx.x * 256 + threadIdx.x;  // 8*256*4096
  int c = (idx >> 12) & 255;
  float xv = isbf ? bf(((const bf16*)x)[idx]) : ((const float*)x)[idx];
  float v = bf(Wy[idx]) * stats[c] + stats[256 + c] + xv;
  if (isbf) ((bf16*)out)[idx] = __float2bfloat16(v);
  else      ((float*)out)[idx] = v;
}

// ---------------------------------------------------------------------------
extern "C" void kernel_launch(void* const* d_in, const int* in_sizes, int n_in,
                              void* d_out, int out_size, void* d_ws, size_t ws_size,
                              hipStream_t stream) {
  const void* x       = d_in[0];
  const void* theta_w = d_in[1];
  const void* theta_b = d_in[2];
  const void* phi_w   = d_in[3];
  const void* phi_b   = d_in[4];
  const void* g_w     = d_in[5];
  const void* g_b     = d_in[6];
  const void* W_w     = d_in[7];
  const void* W_b     = d_in[8];
  const void* gamma   = d_in[9];
  const void* beta    = d_in[10];

  char* wsb = (char*)d_ws;
  // layout (peak ~28 MB):
  //   SCRATCH 0..8.4M      : phi_c then g_c (pre-pool conv outputs)
  //   THETA   8.4..16.8M   : theta
  //   PHI     16.8..18.9M  : pooled phi [B,128,1024]
  //   G       18.9..21.0M  : pooled g   [B,1024,128]
  //   YBUF    21.0..29.4M  : attention output y
  //   W_y bf16 overlays 0..16.8M (SCRATCH+THETA dead after attn)
  bf16*  scratch = (bf16*)(wsb + 0);
  bf16*  theta   = (bf16*)(wsb + 8388608);
  bf16*  phi     = (bf16*)(wsb + 16777216);
  bf16*  gg      = (bf16*)(wsb + 18874368);
  bf16*  ybuf    = (bf16*)(wsb + 20971520);
  bf16*  W_y     = (bf16*)(wsb + 0);
  float* stats   = (float*)(wsb + 29360128);  // 2 KB
  int*   flag    = (int*)  (wsb + 29362176);

  dim3 blk(256);
  dim3 cgrid(64, 8);

  sniff_kernel<<<1, blk, 0, stream>>>((const unsigned short*)x, flag);
  conv1x1_kernel<256, 128, true><<<cgrid, blk, 0, stream>>>(x, phi_w, phi_b, scratch, flag);
  pool_phi_kernel<<<4096, blk, 0, stream>>>(scratch, phi);
  conv1x1_kernel<256, 128, true><<<cgrid, blk, 0, stream>>>(x, g_w, g_b, scratch, flag);
  pool_g_kernel<<<4096, blk, 0, stream>>>(scratch, gg);
  conv1x1_kernel<256, 128, true><<<cgrid, blk, 0, stream>>>(x, theta_w, theta_b, theta, flag);
  attn_kernel<<<cgrid, blk, 0, stream>>>(theta, phi, gg, ybuf);
  conv1x1_kernel<128, 256, false><<<cgrid, blk, 0, stream>>>(ybuf, W_w, W_b, W_y, flag);
  bn_stats_kernel<<<256, blk, 0, stream>>>(W_y, gamma, beta, stats, flag);
  bn_apply_kernel<<<32768, blk, 0, stream>>>(W_y, x, stats, d_out, flag);
}

// Round 3
// 265.720 us; speedup vs baseline: 6.8195x; 6.8195x over previous
//
#include <hip/hip_runtime.h>
#include <hip/hip_bf16.h>
#include <cstdint>
#include <math.h>

using bf16 = __hip_bfloat16;
typedef __attribute__((ext_vector_type(8))) short bf16x8;
typedef __attribute__((ext_vector_type(4))) float f32x4;

#define DEV __device__ __forceinline__

DEV float b2f(unsigned short u) { return __uint_as_float(((uint32_t)u) << 16); }
DEV float bfl(bf16 h) { return __bfloat162float(h); }
DEV short f2bs(float f) { bf16 h = __float2bfloat16(f); return *(short*)&h; }
DEV float ldv(const void* p, int isbf, int i) {
  return isbf ? bfl(((const bf16*)p)[i]) : ((const float*)p)[i];
}

// weight fragment: 8 contiguous elems at w[row*K + off] -> bf16x8
DEV bf16x8 load_wfrag(const void* w, int isbf, int row, int K, int off) {
  bf16x8 r;
  if (isbf) {
    r = *(const bf16x8*)((const short*)w + (size_t)row * K + off);
  } else {
    const float* f = (const float*)w + (size_t)row * K + off;
    float4 a = *(const float4*)f, b = *(const float4*)(f + 4);
    r[0] = f2bs(a.x); r[1] = f2bs(a.y); r[2] = f2bs(a.z); r[3] = f2bs(a.w);
    r[4] = f2bs(b.x); r[5] = f2bs(b.y); r[6] = f2bs(b.z); r[7] = f2bs(b.w);
  }
  return r;
}

// ---------------------------------------------------------------------------
// dtype sniffer (bf16 vs fp32 harness buffers), as validated in round 2.
// ---------------------------------------------------------------------------
__global__ __launch_bounds__(256) void sniff_kernel(
    const unsigned short* __restrict__ xr, int* __restrict__ flag)
{
  int tid = threadIdx.x;
  int good = 0;
  for (int k = tid; k < 16384; k += 256) {
    unsigned short u = xr[2 * k];
    int e = (u >> 7) & 0xFF;
    good += (e >= 0x6A && e <= 0x86) ? 1 : 0;
  }
  __shared__ int r[256];
  r[tid] = good;
  __syncthreads();
  for (int off = 128; off; off >>= 1) {
    if (tid < off) r[tid] += r[tid + off];
    __syncthreads();
  }
  if (tid == 0) *flag = (r[0] > 9830) ? 1 : 0;
}

// ---------------------------------------------------------------------------
// transpose x [b][c(256)][n(4096)] (flag dtype) -> xT [b][n][c] bf16.
// 64x64 tiles via LDS, pad 71 to spread banks.
// ---------------------------------------------------------------------------
__global__ __launch_bounds__(256) void transpose_x(
    const void* __restrict__ x, short* __restrict__ xT, const int* __restrict__ flag)
{
  const int isbf = *flag;
  __shared__ short lt[64 * 71];
  const int n0 = blockIdx.x * 64, c0 = blockIdx.y * 64, b = blockIdx.z;
  const int tid = threadIdx.x;
  for (int it = 0; it < 4; ++it) {
    int idx4 = it * 256 + tid;
    int ci = idx4 >> 4, n4 = (idx4 & 15) * 4;
    size_t go = ((size_t)(b * 256 + c0 + ci)) * 4096 + n0 + n4;
    if (isbf) {
      ushort4 v = *(const ushort4*)((const unsigned short*)x + go);
      lt[ci * 71 + n4 + 0] = v.x; lt[ci * 71 + n4 + 1] = v.y;
      lt[ci * 71 + n4 + 2] = v.z; lt[ci * 71 + n4 + 3] = v.w;
    } else {
      float4 v = *(const float4*)((const float*)x + go);
      lt[ci * 71 + n4 + 0] = f2bs(v.x); lt[ci * 71 + n4 + 1] = f2bs(v.y);
      lt[ci * 71 + n4 + 2] = f2bs(v.z); lt[ci * 71 + n4 + 3] = f2bs(v.w);
    }
  }
  __syncthreads();
  for (int it = 0; it < 4; ++it) {
    int idx4 = it * 256 + tid;
    int n = idx4 >> 4, c4 = (idx4 & 15) * 4;
    ushort4 v;
    v.x = (unsigned short)lt[(c4 + 0) * 71 + n];
    v.y = (unsigned short)lt[(c4 + 1) * 71 + n];
    v.z = (unsigned short)lt[(c4 + 2) * 71 + n];
    v.w = (unsigned short)lt[(c4 + 3) * 71 + n];
    *(ushort4*)(xT + ((size_t)(b * 4096 + n0 + n)) * 256 + c0 + c4) = v;
  }
}

// ---------------------------------------------------------------------------
// conv_t: out[b][n][co=128] = xT[b][n][c=256] @ w[co][c]^T + bias. MFMA.
// A = xT rows (M=n), B = w (N=co, frag-loaded from global), D staged via LDS.
// ---------------------------------------------------------------------------
__global__ __launch_bounds__(256) void conv_t_k(
    const short* __restrict__ xT, const void* __restrict__ w,
    const void* __restrict__ bias, short* __restrict__ out,
    const int* __restrict__ flag)
{
  const int isbf = *flag;
  __shared__ short sh[64 * 264];
  const int b = blockIdx.y, nbase = blockIdx.x * 64, tid = threadIdx.x;
  const int ln = tid & 15, q = (tid >> 4) & 3, wv = tid >> 6;
  for (int it = 0; it < 16; ++it) {
    int idx4 = it * 256 + tid;
    int n = idx4 >> 6, c4 = (idx4 & 63) * 4;
    *(ushort4*)&sh[n * 264 + c4] =
        *(const ushort4*)(xT + ((size_t)(b * 4096 + nbase + n)) * 256 + c4);
  }
  __syncthreads();
  f32x4 zero = {0.f, 0.f, 0.f, 0.f};
  f32x4 acc[4][2];
  for (int nt = 0; nt < 4; ++nt) for (int ti = 0; ti < 2; ++ti) acc[nt][ti] = zero;

  for (int kk = 0; kk < 8; ++kk) {
    int off = kk * 32 + q * 8;
    bf16x8 a[4];
    #pragma unroll
    for (int nt = 0; nt < 4; ++nt)
      a[nt] = *(const bf16x8*)&sh[(16 * nt + ln) * 264 + off];
    #pragma unroll
    for (int ti = 0; ti < 2; ++ti) {
      bf16x8 bw = load_wfrag(w, isbf, 16 * (2 * wv + ti) + ln, 256, off);
      #pragma unroll
      for (int nt = 0; nt < 4; ++nt)
        acc[nt][ti] = __builtin_amdgcn_mfma_f32_16x16x32_bf16(a[nt], bw, acc[nt][ti], 0, 0, 0);
    }
  }
  __syncthreads();
  float bv[2];
  for (int ti = 0; ti < 2; ++ti) bv[ti] = ldv(bias, isbf, 16 * (2 * wv + ti) + ln);
  for (int nt = 0; nt < 4; ++nt)
    for (int ti = 0; ti < 2; ++ti)
      for (int r = 0; r < 4; ++r)
        sh[(16 * nt + q * 4 + r) * 136 + 16 * (2 * wv + ti) + ln] =
            f2bs(acc[nt][ti][r] + bv[ti]);
  __syncthreads();
  for (int it = 0; it < 8; ++it) {
    int idx4 = it * 256 + tid;
    int n = idx4 >> 5, c4 = (idx4 & 31) * 4;
    *(ushort4*)(out + ((size_t)(b * 4096 + nbase + n)) * 128 + c4) =
        *(const ushort4*)&sh[n * 136 + c4];
  }
}

// ---------------------------------------------------------------------------
// conv_n: out[b][CO][n] = w[CO][K] @ inp[b][n][K]^T + bias. MFMA.
// A = w (M=co, global frags), B = inp rows (k-contiguous), D staged via LDS.
// ---------------------------------------------------------------------------
template<int CO, int K>
__global__ __launch_bounds__(256) void conv_n_k(
    const short* __restrict__ inp, const void* __restrict__ w,
    const void* __restrict__ bias, short* __restrict__ out,
    const int* __restrict__ flag)
{
  const int isbf = *flag;
  constexpr int XS = 64 * (K + 8);
  constexpr int OS = CO * 68;
  __shared__ short sh[(XS > OS ? XS : OS)];
  const int b = blockIdx.y, nbase = blockIdx.x * 64, tid = threadIdx.x;
  const int ln = tid & 15, q = (tid >> 4) & 3, wv = tid >> 6;
  constexpr int TPW = CO / 64;
  constexpr int KS = (K == 256) ? 6 : 5;
  for (int it = 0; it < 64 * K / 1024; ++it) {
    int idx4 = it * 256 + tid;
    int n = idx4 >> KS, c4 = (idx4 & ((K / 4) - 1)) * 4;
    *(ushort4*)&sh[n * (K + 8) + c4] =
        *(const ushort4*)(inp + ((size_t)(b * 4096 + nbase + n)) * K + c4);
  }
  __syncthreads();
  f32x4 zero = {0.f, 0.f, 0.f, 0.f};
  f32x4 acc[TPW][4];
  for (int ti = 0; ti < TPW; ++ti) for (int nt = 0; nt < 4; ++nt) acc[ti][nt] = zero;

  for (int kk = 0; kk < K / 32; ++kk) {
    int off = kk * 32 + q * 8;
    bf16x8 bx[4];
    #pragma unroll
    for (int nt = 0; nt < 4; ++nt)
      bx[nt] = *(const bf16x8*)&sh[(16 * nt + ln) * (K + 8) + off];
    #pragma unroll
    for (int ti = 0; ti < TPW; ++ti) {
      bf16x8 aw = load_wfrag(w, isbf, 16 * (TPW * wv + ti) + ln, K, off);
      #pragma unroll
      for (int nt = 0; nt < 4; ++nt)
        acc[ti][nt] = __builtin_amdgcn_mfma_f32_16x16x32_bf16(aw, bx[nt], acc[ti][nt], 0, 0, 0);
    }
  }
  __syncthreads();
  for (int ti = 0; ti < TPW; ++ti)
    for (int r = 0; r < 4; ++r) {
      int co = 16 * (TPW * wv + ti) + q * 4 + r;
      float bb = ldv(bias, isbf, co);
      for (int nt = 0; nt < 4; ++nt)
        sh[co * 68 + 16 * nt + ln] = f2bs(acc[ti][nt][r] + bb);
    }
  __syncthreads();
  for (int it = 0; it < 64 * CO / 1024; ++it) {
    int idx4 = it * 256 + tid;
    int co = idx4 >> 4, n4 = (idx4 & 15) * 4;
    *(ushort4*)(out + ((size_t)(b * CO + co)) * 4096 + nbase + n4) =
        *(const ushort4*)&sh[co * 68 + n4];
  }
}

// ---------------------------------------------------------------------------
// pools. phi_c is n-major [b][n][ci] -> phi [b][m][ci]; g_c is c-major
// [b][ci][n] -> g [b][ci][m].
// ---------------------------------------------------------------------------
__global__ __launch_bounds__(256) void pool_phi_kernel(
    const short* __restrict__ pc, short* __restrict__ phi)
{
  int idx = blockIdx.x * 256 + threadIdx.x;  // b*1024*128
  int ci = idx & 127, m = (idx >> 7) & 1023, b = idx >> 17;
  int mh = m >> 5, mw = m & 31;
  const short* p = pc + ((size_t)(b * 4096 + (mh * 2) * 64 + mw * 2)) * 128 + ci;
  float v = fmaxf(fmaxf(b2f(p[0]), b2f(p[128])),
                  fmaxf(b2f(p[64 * 128]), b2f(p[65 * 128])));
  phi[idx] = f2bs(v);
}

__global__ __launch_bounds__(256) void pool_g_kernel(
    const short* __restrict__ gc, short* __restrict__ g)
{
  int idx = blockIdx.x * 256 + threadIdx.x;  // (b*128+ci)*1024 + m
  int m = idx & 1023, bc = idx >> 10;
  int mh = m >> 5, mw = m & 31;
  const short* p = gc + (size_t)bc * 4096 + mh * 128 + mw * 2;
  float v = fmaxf(fmaxf(b2f(p[0]), b2f(p[1])), fmaxf(b2f(p[64]), b2f(p[65])));
  g[idx] = f2bs(v);
}

// ---------------------------------------------------------------------------
// MFMA flash attention. theta [b][n][ci], phi [b][m][ci], g [b][ci][m],
// y out [b][n][ci]. Block = (64-n tile, b); 4 waves, 16 chunks of 64 m.
// Per wave/chunk: 16 MFMA (S) + 16 MFMA (y) + 2 MFMA (row sums vs ones).
// Row-sum accumulator rows coincide with yacc rows -> register normalize.
// ---------------------------------------------------------------------------
__global__ __launch_bounds__(256) void attn_kernel(
    const short* __restrict__ theta, const short* __restrict__ phi,
    const short* __restrict__ g, short* __restrict__ y)
{
  __shared__ short th[64 * 136];
  __shared__ short ph[64 * 136];
  __shared__ short gl[128 * 72];
  __shared__ short Pl[64 * 72];
  const int b = blockIdx.y, nbase = blockIdx.x * 64, tid = threadIdx.x;
  const int ln = tid & 15, q = (tid >> 4) & 3, wv = tid >> 6;

  for (int it = 0; it < 8; ++it) {
    int idx4 = it * 256 + tid;
    int n = idx4 >> 5, c4 = (idx4 & 31) * 4;
    *(ushort4*)&th[n * 136 + c4] =
        *(const ushort4*)(theta + ((size_t)(b * 4096 + nbase + n)) * 128 + c4);
  }

  f32x4 zero = {0.f, 0.f, 0.f, 0.f};
  f32x4 yacc[8], lacc = zero;
  for (int t = 0; t < 8; ++t) yacc[t] = zero;
  bf16x8 ones;
  #pragma unroll
  for (int j = 0; j < 8; ++j) ones[j] = 0x3F80;  // bf16(1.0)

  for (int mc = 0; mc < 16; ++mc) {
    __syncthreads();  // th ready (first) / prev chunk's ph,gl consumed
    for (int it = 0; it < 8; ++it) {
      int idx4 = it * 256 + tid;
      int m = idx4 >> 5, c4 = (idx4 & 31) * 4;
      *(ushort4*)&ph[m * 136 + c4] =
          *(const ushort4*)(phi + ((size_t)(b * 1024 + mc * 64 + m)) * 128 + c4);
    }
    for (int it = 0; it < 8; ++it) {
      int idx4 = it * 256 + tid;
      int ci = idx4 >> 4, m4 = (idx4 & 15) * 4;
      *(ushort4*)&gl[ci * 72 + m4] =
          *(const ushort4*)(g + ((size_t)(b * 128 + ci)) * 1024 + mc * 64 + m4);
    }
    __syncthreads();  // ph, gl ready

    bf16x8 a[4];
    #pragma unroll
    for (int kk = 0; kk < 4; ++kk)
      a[kk] = *(const bf16x8*)&th[(16 * wv + ln) * 136 + kk * 32 + q * 8];
    #pragma unroll
    for (int t = 0; t < 4; ++t) {
      f32x4 s = zero;
      #pragma unroll
      for (int kk = 0; kk < 4; ++kk) {
        bf16x8 bp = *(const bf16x8*)&ph[(16 * t + ln) * 136 + kk * 32 + q * 8];
        s = __builtin_amdgcn_mfma_f32_16x16x32_bf16(a[kk], bp, s, 0, 0, 0);
      }
      #pragma unroll
      for (int r = 0; r < 4; ++r)
        Pl[(16 * wv + q * 4 + r) * 72 + 16 * t + ln] =
            f2bs(__expf(fminf(s[r], 80.f)));
    }
    // Pl rows 16*wv..+15 are wave-local: no barrier needed, lgkmcnt orders.
    bf16x8 ap[2];
    #pragma unroll
    for (int kk = 0; kk < 2; ++kk)
      ap[kk] = *(const bf16x8*)&Pl[(16 * wv + ln) * 72 + kk * 32 + q * 8];
    #pragma unroll
    for (int kk = 0; kk < 2; ++kk)
      lacc = __builtin_amdgcn_mfma_f32_16x16x32_bf16(ap[kk], ones, lacc, 0, 0, 0);
    #pragma unroll
    for (int t = 0; t < 8; ++t) {
      #pragma unroll
      for (int kk = 0; kk < 2; ++kk) {
        bf16x8 bg = *(const bf16x8*)&gl[(16 * t + ln) * 72 + kk * 32 + q * 8];
        yacc[t] = __builtin_amdgcn_mfma_f32_16x16x32_bf16(ap[kk], bg, yacc[t], 0, 0, 0);
      }
    }
  }
  __syncthreads();  // all waves done with ph before reuse as staging

  float li[4];
  #pragma unroll
  for (int r = 0; r < 4; ++r) li[r] = 1.0f / lacc[r];
  for (int t = 0; t < 8; ++t)
    for (int r = 0; r < 4; ++r)
      ph[(16 * wv + q * 4 + r) * 136 + 16 * t + ln] = f2bs(yacc[t][r] * li[r]);
  __syncthreads();
  for (int it = 0; it < 8; ++it) {
    int idx4 = it * 256 + tid;
    int n = idx4 >> 5, c4 = (idx4 & 31) * 4;
    *(ushort4*)(y + ((size_t)(b * 4096 + nbase + n)) * 128 + c4) =
        *(const ushort4*)&ph[n * 136 + c4];
  }
}

// ---------------------------------------------------------------------------
// BatchNorm stats + apply w/ residual. W_y is bf16 [b][256][4096].
// ---------------------------------------------------------------------------
__global__ __launch_bounds__(256) void bn_stats_kernel(
    const short* __restrict__ Wy, const void* __restrict__ gamma,
    const void* __restrict__ beta, float* __restrict__ stats,
    const int* __restrict__ flag)
{
  const int isbf = *flag;
  const int c = blockIdx.x;
  const int tid = threadIdx.x;
  float s = 0.f, s2 = 0.f;
  for (int b = 0; b < 8; ++b) {
    const short* p = Wy + ((size_t)(b * 256 + c)) * 4096;
    for (int i = tid; i < 4096; i += 256) {
      float v = b2f(p[i]);
      s += v; s2 += v * v;
    }
  }
  __shared__ float rs[256], rs2[256];
  rs[tid] = s; rs2[tid] = s2;
  __syncthreads();
  for (int off = 128; off > 0; off >>= 1) {
    if (tid < off) { rs[tid] += rs[tid + off]; rs2[tid] += rs2[tid + off]; }
    __syncthreads();
  }
  if (tid == 0) {
    float mean = rs[0] * (1.0f / 32768.0f);
    float var = rs2[0] * (1.0f / 32768.0f) - mean * mean;
    var = fmaxf(var, 0.f);
    float rstd = rsqrtf(var + 1e-5f);
    float scale = rstd * ldv(gamma, isbf, c);
    stats[c] = scale;
    stats[256 + c] = ldv(beta, isbf, c) - mean * scale;
  }
}

__global__ __launch_bounds__(256) void bn_apply_kernel(
    const short* __restrict__ Wy, const void* __restrict__ x,
    const float* __restrict__ stats, void* __restrict__ out,
    const int* __restrict__ flag)
{
  const int isbf = *flag;
  int idx = blockIdx.x * 256 + threadIdx.x;  // 8*256*4096
  int c = (idx >> 12) & 255;
  float xv = isbf ? bfl(((const bf16*)x)[idx]) : ((const float*)x)[idx];
  float v = b2f(Wy[idx]) * stats[c] + stats[256 + c] + xv;
  if (isbf) ((bf16*)out)[idx] = __float2bfloat16(v);
  else      ((float*)out)[idx] = v;
}

// ---------------------------------------------------------------------------
extern "C" void kernel_launch(void* const* d_in, const int* in_sizes, int n_in,
                              void* d_out, int out_size, void* d_ws, size_t ws_size,
                              hipStream_t stream) {
  const void* x       = d_in[0];
  const void* theta_w = d_in[1];
  const void* theta_b = d_in[2];
  const void* phi_w   = d_in[3];
  const void* phi_b   = d_in[4];
  const void* g_w     = d_in[5];
  const void* g_b     = d_in[6];
  const void* W_w     = d_in[7];
  const void* W_b     = d_in[8];
  const void* gamma   = d_in[9];
  const void* beta    = d_in[10];

  char* wsb = (char*)d_ws;
  // Aliasing plan (peak 37.75 MB):
  //   [0, 16.78M)      xT  -> later y (xT dead after g-conv; attn only needs
  //                          theta/phi/g, writes y into first 8.39M)
  //   [16.78M, 25.17M) theta -> later W_y first half
  //   [25.17M, 33.55M) scratchA (phi_c then g_c) -> later W_y second half
  //   [33.55M, 35.65M) phi   [b][m][ci]
  //   [35.65M, 37.75M) g     [b][ci][m]
  //   [37.75M+)        stats, flag
  short* xT      = (short*)(wsb + 0);
  short* ybuf    = (short*)(wsb + 0);
  short* theta   = (short*)(wsb + 16777216);
  short* W_y     = (short*)(wsb + 16777216);
  short* scratch = (short*)(wsb + 25165824);
  short* phi     = (short*)(wsb + 33554432);
  short* gg      = (short*)(wsb + 35651584);
  float* stats   = (float*)(wsb + 37748736);
  int*   flag    = (int*)  (wsb + 37750784);

  dim3 blk(256);
  dim3 cgrid(64, 8);
  dim3 tgrid(64, 4, 8);

  sniff_kernel<<<1, blk, 0, stream>>>((const unsigned short*)x, flag);
  transpose_x<<<tgrid, blk, 0, stream>>>(x, xT, flag);
  conv_t_k<<<cgrid, blk, 0, stream>>>(xT, theta_w, theta_b, theta, flag);
  conv_t_k<<<cgrid, blk, 0, stream>>>(xT, phi_w, phi_b, scratch, flag);
  pool_phi_kernel<<<4096, blk, 0, stream>>>(scratch, phi);
  conv_n_k<128, 256><<<cgrid, blk, 0, stream>>>(xT, g_w, g_b, scratch, flag);
  pool_g_kernel<<<4096, blk, 0, stream>>>(scratch, gg);
  attn_kernel<<<cgrid, blk, 0, stream>>>(theta, phi, gg, ybuf);
  conv_n_k<256, 128><<<cgrid, blk, 0, stream>>>(ybuf, W_w, W_b, W_y, flag);
  bn_stats_kernel<<<256, blk, 0, stream>>>(W_y, gamma, beta, stats, flag);
  bn_apply_kernel<<<32768, blk, 0, stream>>>(W_y, x, stats, d_out, flag);
}

// Round 7
// 241.044 us; speedup vs baseline: 7.5177x; 1.1024x over previous
//
#include <hip/hip_runtime.h>
#include <hip/hip_bf16.h>
#include <cstdint>
#include <math.h>

using bf16 = __hip_bfloat16;
typedef __attribute__((ext_vector_type(8))) short bf16x8;
typedef __attribute__((ext_vector_type(4))) float f32x4;

#define DEV __device__ __forceinline__

DEV float b2f(unsigned short u) { return __uint_as_float(((uint32_t)u) << 16); }
DEV float bfl(bf16 h) { return __bfloat162float(h); }
DEV short f2bs(float f) { bf16 h = __float2bfloat16(f); return *(short*)&h; }
// explicit bf16-pair pack: a in low 16 bits (lower address), b in high.
DEV uint32_t pk2(float a, float b) {
  return (uint32_t)(unsigned short)f2bs(a) |
         ((uint32_t)(unsigned short)f2bs(b) << 16);
}
DEV float ldv(const void* p, int isbf, int i) {
  return isbf ? bfl(((const bf16*)p)[i]) : ((const float*)p)[i];
}

// weight fragment: 8 contiguous elems at w[row*K + off] -> bf16x8
DEV bf16x8 load_wfrag(const void* w, int isbf, int row, int K, int off) {
  bf16x8 r;
  if (isbf) {
    r = *(const bf16x8*)((const short*)w + (size_t)row * K + off);
  } else {
    const float* f = (const float*)w + (size_t)row * K + off;
    float4 a = *(const float4*)f, b = *(const float4*)(f + 4);
    r[0] = f2bs(a.x); r[1] = f2bs(a.y); r[2] = f2bs(a.z); r[3] = f2bs(a.w);
    r[4] = f2bs(b.x); r[5] = f2bs(b.y); r[6] = f2bs(b.z); r[7] = f2bs(b.w);
  }
  return r;
}

// ---------------------------------------------------------------------------
// dtype sniffer — EXACT round-3 version (validated).
// ---------------------------------------------------------------------------
__global__ __launch_bounds__(256) void sniff_kernel(
    const unsigned short* __restrict__ xr, int* __restrict__ flag)
{
  int tid = threadIdx.x;
  int good = 0;
  for (int k = tid; k < 16384; k += 256) {
    unsigned short u = xr[2 * k];
    int e = (u >> 7) & 0xFF;
    good += (e >= 0x6A && e <= 0x86) ? 1 : 0;
  }
  __shared__ int r[256];
  r[tid] = good;
  __syncthreads();
  for (int off = 128; off; off >>= 1) {
    if (tid < off) r[tid] += r[tid + off];
    __syncthreads();
  }
  if (tid == 0) *flag = (r[0] > 9830) ? 1 : 0;
}

// ---------------------------------------------------------------------------
// transpose x [b][c(256)][n(4096)] (flag dtype) -> xT [b][n][c] bf16.
// EXACT round-3 version (validated).
// ---------------------------------------------------------------------------
__global__ __launch_bounds__(256) void transpose_x(
    const void* __restrict__ x, short* __restrict__ xT, const int* __restrict__ flag)
{
  const int isbf = *flag;
  __shared__ short lt[64 * 71];
  const int n0 = blockIdx.x * 64, c0 = blockIdx.y * 64, b = blockIdx.z;
  const int tid = threadIdx.x;
  for (int it = 0; it < 4; ++it) {
    int idx4 = it * 256 + tid;
    int ci = idx4 >> 4, n4 = (idx4 & 15) * 4;
    size_t go = ((size_t)(b * 256 + c0 + ci)) * 4096 + n0 + n4;
    if (isbf) {
      ushort4 v = *(const ushort4*)((const unsigned short*)x + go);
      lt[ci * 71 + n4 + 0] = v.x; lt[ci * 71 + n4 + 1] = v.y;
      lt[ci * 71 + n4 + 2] = v.z; lt[ci * 71 + n4 + 3] = v.w;
    } else {
      float4 v = *(const float4*)((const float*)x + go);
      lt[ci * 71 + n4 + 0] = f2bs(v.x); lt[ci * 71 + n4 + 1] = f2bs(v.y);
      lt[ci * 71 + n4 + 2] = f2bs(v.z); lt[ci * 71 + n4 + 3] = f2bs(v.w);
    }
  }
  __syncthreads();
  for (int it = 0; it < 4; ++it) {
    int idx4 = it * 256 + tid;
    int n = idx4 >> 4, c4 = (idx4 & 15) * 4;
    ushort4 v;
    v.x = (unsigned short)lt[(c4 + 0) * 71 + n];
    v.y = (unsigned short)lt[(c4 + 1) * 71 + n];
    v.z = (unsigned short)lt[(c4 + 2) * 71 + n];
    v.w = (unsigned short)lt[(c4 + 3) * 71 + n];
    *(ushort4*)(xT + ((size_t)(b * 4096 + n0 + n)) * 256 + c0 + c4) = v;
  }
}

// ---------------------------------------------------------------------------
// conv_t: out[b][n][co=128] — EXACT round-3 version (validated).
// ---------------------------------------------------------------------------
__global__ __launch_bounds__(256) void conv_t_k(
    const short* __restrict__ xT, const void* __restrict__ w,
    const void* __restrict__ bias, short* __restrict__ out,
    const int* __restrict__ flag)
{
  const int isbf = *flag;
  __shared__ short sh[64 * 264];
  const int b = blockIdx.y, nbase = blockIdx.x * 64, tid = threadIdx.x;
  const int ln = tid & 15, q = (tid >> 4) & 3, wv = tid >> 6;
  for (int it = 0; it < 16; ++it) {
    int idx4 = it * 256 + tid;
    int n = idx4 >> 6, c4 = (idx4 & 63) * 4;
    *(ushort4*)&sh[n * 264 + c4] =
        *(const ushort4*)(xT + ((size_t)(b * 4096 + nbase + n)) * 256 + c4);
  }
  __syncthreads();
  f32x4 zero = {0.f, 0.f, 0.f, 0.f};
  f32x4 acc[4][2];
  for (int nt = 0; nt < 4; ++nt) for (int ti = 0; ti < 2; ++ti) acc[nt][ti] = zero;

  for (int kk = 0; kk < 8; ++kk) {
    int off = kk * 32 + q * 8;
    bf16x8 a[4];
    #pragma unroll
    for (int nt = 0; nt < 4; ++nt)
      a[nt] = *(const bf16x8*)&sh[(16 * nt + ln) * 264 + off];
    #pragma unroll
    for (int ti = 0; ti < 2; ++ti) {
      bf16x8 bw = load_wfrag(w, isbf, 16 * (2 * wv + ti) + ln, 256, off);
      #pragma unroll
      for (int nt = 0; nt < 4; ++nt)
        acc[nt][ti] = __builtin_amdgcn_mfma_f32_16x16x32_bf16(a[nt], bw, acc[nt][ti], 0, 0, 0);
    }
  }
  __syncthreads();
  float bv[2];
  for (int ti = 0; ti < 2; ++ti) bv[ti] = ldv(bias, isbf, 16 * (2 * wv + ti) + ln);
  for (int nt = 0; nt < 4; ++nt)
    for (int ti = 0; ti < 2; ++ti)
      for (int r = 0; r < 4; ++r)
        sh[(16 * nt + q * 4 + r) * 136 + 16 * (2 * wv + ti) + ln] =
            f2bs(acc[nt][ti][r] + bv[ti]);
  __syncthreads();
  for (int it = 0; it < 8; ++it) {
    int idx4 = it * 256 + tid;
    int n = idx4 >> 5, c4 = (idx4 & 31) * 4;
    *(ushort4*)(out + ((size_t)(b * 4096 + nbase + n)) * 128 + c4) =
        *(const ushort4*)&sh[n * 136 + c4];
  }
}

// ---------------------------------------------------------------------------
// conv_n: out[b][CO][n] — EXACT round-3 version (validated).
// ---------------------------------------------------------------------------
template<int CO, int K>
__global__ __launch_bounds__(256) void conv_n_k(
    const short* __restrict__ inp, const void* __restrict__ w,
    const void* __restrict__ bias, short* __restrict__ out,
    const int* __restrict__ flag)
{
  const int isbf = *flag;
  constexpr int XS = 64 * (K + 8);
  constexpr int OS = CO * 68;
  __shared__ short sh[(XS > OS ? XS : OS)];
  const int b = blockIdx.y, nbase = blockIdx.x * 64, tid = threadIdx.x;
  const int ln = tid & 15, q = (tid >> 4) & 3, wv = tid >> 6;
  constexpr int TPW = CO / 64;
  constexpr int KS = (K == 256) ? 6 : 5;
  for (int it = 0; it < 64 * K / 1024; ++it) {
    int idx4 = it * 256 + tid;
    int n = idx4 >> KS, c4 = (idx4 & ((K / 4) - 1)) * 4;
    *(ushort4*)&sh[n * (K + 8) + c4] =
        *(const ushort4*)(inp + ((size_t)(b * 4096 + nbase + n)) * K + c4);
  }
  __syncthreads();
  f32x4 zero = {0.f, 0.f, 0.f, 0.f};
  f32x4 acc[TPW][4];
  for (int ti = 0; ti < TPW; ++ti) for (int nt = 0; nt < 4; ++nt) acc[ti][nt] = zero;

  for (int kk = 0; kk < K / 32; ++kk) {
    int off = kk * 32 + q * 8;
    bf16x8 bx[4];
    #pragma unroll
    for (int nt = 0; nt < 4; ++nt)
      bx[nt] = *(const bf16x8*)&sh[(16 * nt + ln) * (K + 8) + off];
    #pragma unroll
    for (int ti = 0; ti < TPW; ++ti) {
      bf16x8 aw = load_wfrag(w, isbf, 16 * (TPW * wv + ti) + ln, K, off);
      #pragma unroll
      for (int nt = 0; nt < 4; ++nt)
        acc[ti][nt] = __builtin_amdgcn_mfma_f32_16x16x32_bf16(aw, bx[nt], acc[ti][nt], 0, 0, 0);
    }
  }
  __syncthreads();
  for (int ti = 0; ti < TPW; ++ti)
    for (int r = 0; r < 4; ++r) {
      int co = 16 * (TPW * wv + ti) + q * 4 + r;
      float bb = ldv(bias, isbf, co);
      for (int nt = 0; nt < 4; ++nt)
        sh[co * 68 + 16 * nt + ln] = f2bs(acc[ti][nt][r] + bb);
    }
  __syncthreads();
  for (int it = 0; it < 64 * CO / 1024; ++it) {
    int idx4 = it * 256 + tid;
    int co = idx4 >> 4, n4 = (idx4 & 15) * 4;
    *(ushort4*)(out + ((size_t)(b * CO + co)) * 4096 + nbase + n4) =
        *(const ushort4*)&sh[co * 68 + n4];
  }
}

// ---------------------------------------------------------------------------
// pools — EXACT round-3 versions (validated).
// ---------------------------------------------------------------------------
__global__ __launch_bounds__(256) void pool_phi_kernel(
    const short* __restrict__ pc, short* __restrict__ phi)
{
  int idx = blockIdx.x * 256 + threadIdx.x;  // b*1024*128
  int ci = idx & 127, m = (idx >> 7) & 1023, b = idx >> 17;
  int mh = m >> 5, mw = m & 31;
  const short* p = pc + ((size_t)(b * 4096 + (mh * 2) * 64 + mw * 2)) * 128 + ci;
  float v = fmaxf(fmaxf(b2f(p[0]), b2f(p[128])),
                  fmaxf(b2f(p[64 * 128]), b2f(p[65 * 128])));
  phi[idx] = f2bs(v);
}

__global__ __launch_bounds__(256) void pool_g_kernel(
    const short* __restrict__ gc, short* __restrict__ g)
{
  int idx = blockIdx.x * 256 + threadIdx.x;  // (b*128+ci)*1024 + m
  int m = idx & 1023, bc = idx >> 10;
  int mh = m >> 5, mw = m & 31;
  const short* p = gc + (size_t)bc * 4096 + mh * 128 + mw * 2;
  float v = fmaxf(fmaxf(b2f(p[0]), b2f(p[1])), fmaxf(b2f(p[64]), b2f(p[65])));
  g[idx] = f2bs(v);
}

// ---------------------------------------------------------------------------
// MFMA flash attention — EXACT round-3 version (validated).
// ---------------------------------------------------------------------------
__global__ __launch_bounds__(256) void attn_kernel(
    const short* __restrict__ theta, const short* __restrict__ phi,
    const short* __restrict__ g, short* __restrict__ y)
{
  __shared__ short th[64 * 136];
  __shared__ short ph[64 * 136];
  __shared__ short gl[128 * 72];
  __shared__ short Pl[64 * 72];
  const int b = blockIdx.y, nbase = blockIdx.x * 64, tid = threadIdx.x;
  const int ln = tid & 15, q = (tid >> 4) & 3, wv = tid >> 6;

  for (int it = 0; it < 8; ++it) {
    int idx4 = it * 256 + tid;
    int n = idx4 >> 5, c4 = (idx4 & 31) * 4;
    *(ushort4*)&th[n * 136 + c4] =
        *(const ushort4*)(theta + ((size_t)(b * 4096 + nbase + n)) * 128 + c4);
  }

  f32x4 zero = {0.f, 0.f, 0.f, 0.f};
  f32x4 yacc[8], lacc = zero;
  for (int t = 0; t < 8; ++t) yacc[t] = zero;
  bf16x8 ones;
  #pragma unroll
  for (int j = 0; j < 8; ++j) ones[j] = 0x3F80;

  for (int mc = 0; mc < 16; ++mc) {
    __syncthreads();
    for (int it = 0; it < 8; ++it) {
      int idx4 = it * 256 + tid;
      int m = idx4 >> 5, c4 = (idx4 & 31) * 4;
      *(ushort4*)&ph[m * 136 + c4] =
          *(const ushort4*)(phi + ((size_t)(b * 1024 + mc * 64 + m)) * 128 + c4);
    }
    for (int it = 0; it < 8; ++it) {
      int idx4 = it * 256 + tid;
      int ci = idx4 >> 4, m4 = (idx4 & 15) * 4;
      *(ushort4*)&gl[ci * 72 + m4] =
          *(const ushort4*)(g + ((size_t)(b * 128 + ci)) * 1024 + mc * 64 + m4);
    }
    __syncthreads();

    bf16x8 a[4];
    #pragma unroll
    for (int kk = 0; kk < 4; ++kk)
      a[kk] = *(const bf16x8*)&th[(16 * wv + ln) * 136 + kk * 32 + q * 8];
    #pragma unroll
    for (int t = 0; t < 4; ++t) {
      f32x4 s = zero;
      #pragma unroll
      for (int kk = 0; kk < 4; ++kk) {
        bf16x8 bp = *(const bf16x8*)&ph[(16 * t + ln) * 136 + kk * 32 + q * 8];
        s = __builtin_amdgcn_mfma_f32_16x16x32_bf16(a[kk], bp, s, 0, 0, 0);
      }
      #pragma unroll
      for (int r = 0; r < 4; ++r)
        Pl[(16 * wv + q * 4 + r) * 72 + 16 * t + ln] =
            f2bs(__expf(fminf(s[r], 80.f)));
    }
    bf16x8 ap[2];
    #pragma unroll
    for (int kk = 0; kk < 2; ++kk)
      ap[kk] = *(const bf16x8*)&Pl[(16 * wv + ln) * 72 + kk * 32 + q * 8];
    #pragma unroll
    for (int kk = 0; kk < 2; ++kk)
      lacc = __builtin_amdgcn_mfma_f32_16x16x32_bf16(ap[kk], ones, lacc, 0, 0, 0);
    #pragma unroll
    for (int t = 0; t < 8; ++t) {
      #pragma unroll
      for (int kk = 0; kk < 2; ++kk) {
        bf16x8 bg = *(const bf16x8*)&gl[(16 * t + ln) * 72 + kk * 32 + q * 8];
        yacc[t] = __builtin_amdgcn_mfma_f32_16x16x32_bf16(ap[kk], bg, yacc[t], 0, 0, 0);
      }
    }
  }
  __syncthreads();

  float li[4];
  #pragma unroll
  for (int r = 0; r < 4; ++r) li[r] = 1.0f / lacc[r];
  for (int t = 0; t < 8; ++t)
    for (int r = 0; r < 4; ++r)
      ph[(16 * wv + q * 4 + r) * 136 + 16 * t + ln] = f2bs(yacc[t][r] * li[r]);
  __syncthreads();
  for (int it = 0; it < 8; ++it) {
    int idx4 = it * 256 + tid;
    int n = idx4 >> 5, c4 = (idx4 & 31) * 4;
    *(ushort4*)(y + ((size_t)(b * 4096 + nbase + n)) * 128 + c4) =
        *(const ushort4*)&ph[n * 136 + c4];
  }
}

// ---------------------------------------------------------------------------
// conv_W + BN partial-stat atomics — UNDER TEST (round-4 version).
// ---------------------------------------------------------------------------
__global__ __launch_bounds__(256, 4) void convW_k(
    const short* __restrict__ yb, const void* __restrict__ w,
    const void* __restrict__ bias, short* __restrict__ Wy,
    float* __restrict__ stats, const int* __restrict__ flag)
{
  const int isbf = *flag;
  __shared__ short sh[256 * 72];
  const int b = blockIdx.y, nbase = blockIdx.x * 64, tid = threadIdx.x;
  const int ln = tid & 15, q = (tid >> 4) & 3, wv = tid >> 6;

  for (int it = 0; it < 4; ++it) {
    int idx8 = it * 256 + tid;
    int n = idx8 >> 4, c8 = (idx8 & 15) * 8;
    *(uint4*)&sh[n * 136 + c8] =
        *(const uint4*)(yb + ((size_t)(b * 4096 + nbase + n)) * 128 + c8);
  }
  __syncthreads();
  f32x4 zero = {0.f, 0.f, 0.f, 0.f};
  f32x4 acc[4][4];
  for (int ti = 0; ti < 4; ++ti)
    for (int nt = 0; nt < 4; ++nt) acc[ti][nt] = zero;

  for (int kk = 0; kk < 4; ++kk) {
    int off = kk * 32 + q * 8;
    bf16x8 bx[4];
    #pragma unroll
    for (int nt = 0; nt < 4; ++nt)
      bx[nt] = *(const bf16x8*)&sh[(16 * nt + ln) * 136 + off];
    #pragma unroll
    for (int ti = 0; ti < 4; ++ti) {
      bf16x8 aw = load_wfrag(w, isbf, 16 * (4 * wv + ti) + ln, 128, off);
      #pragma unroll
      for (int nt = 0; nt < 4; ++nt)
        acc[ti][nt] = __builtin_amdgcn_mfma_f32_16x16x32_bf16(aw, bx[nt], acc[ti][nt], 0, 0, 0);
    }
  }
  __syncthreads();
  #pragma unroll
  for (int ti = 0; ti < 4; ++ti)
    #pragma unroll
    for (int r = 0; r < 4; ++r) {
      int co = 16 * (4 * wv + ti) + 4 * q + r;
      float bb = ldv(bias, isbf, co);
      #pragma unroll
      for (int nt = 0; nt < 4; ++nt)
        sh[co * 72 + 16 * nt + ln] = f2bs(acc[ti][nt][r] + bb);
    }
  __syncthreads();
  {
    int co = tid;
    float s = 0.f, s2 = 0.f;
    for (int i = 0; i < 64; ++i) {
      float v = b2f((unsigned short)sh[co * 72 + i]);
      s += v; s2 += v * v;
    }
    atomicAdd(&stats[co], s);
    atomicAdd(&stats[256 + co], s2);
  }
  for (int it = 0; it < 8; ++it) {
    int idx8 = it * 256 + tid;
    int co = idx8 >> 3, n8 = (idx8 & 7) * 8;
    *(uint4*)(Wy + ((size_t)(b * 256 + co)) * 4096 + nbase + n8) =
        *(const uint4*)&sh[co * 72 + n8];
  }
}

// ---------------------------------------------------------------------------
// BN apply + residual, x4 — UNDER TEST (round-4/6 version, explicit pk2).
// ---------------------------------------------------------------------------
__global__ __launch_bounds__(256) void bn_apply4(
    const short* __restrict__ Wy, const void* __restrict__ x,
    const float* __restrict__ stats, const void* __restrict__ gamma,
    const void* __restrict__ beta, void* __restrict__ out,
    const int* __restrict__ flag)
{
  const int isbf = *flag;
  int t = blockIdx.x * 256 + threadIdx.x;
  int idx4 = t * 4;
  int c = (idx4 >> 12) & 255;
  float s = stats[c], s2 = stats[256 + c];
  float mean = s * (1.0f / 32768.0f);
  float var = fmaxf(s2 * (1.0f / 32768.0f) - mean * mean, 0.f);
  float scale = rsqrtf(var + 1e-5f) * ldv(gamma, isbf, c);
  float shift = ldv(beta, isbf, c) - mean * scale;
  ushort4 wy = *(const ushort4*)(Wy + idx4);
  float xv[4];
  if (isbf) {
    ushort4 xu = *(const ushort4*)((const unsigned short*)x + idx4);
    xv[0] = b2f(xu.x); xv[1] = b2f(xu.y); xv[2] = b2f(xu.z); xv[3] = b2f(xu.w);
  } else {
    float4 xf = *(const float4*)((const float*)x + idx4);
    xv[0] = xf.x; xv[1] = xf.y; xv[2] = xf.z; xv[3] = xf.w;
  }
  float v0 = b2f(wy.x) * scale + shift + xv[0];
  float v1 = b2f(wy.y) * scale + shift + xv[1];
  float v2 = b2f(wy.z) * scale + shift + xv[2];
  float v3 = b2f(wy.w) * scale + shift + xv[3];
  if (isbf) {
    uint2 o; o.x = pk2(v0, v1); o.y = pk2(v2, v3);
    *(uint2*)((unsigned short*)out + idx4) = o;
  } else {
    float4 o = make_float4(v0, v1, v2, v3);
    *(float4*)((float*)out + idx4) = o;
  }
}

// ---------------------------------------------------------------------------
extern "C" void kernel_launch(void* const* d_in, const int* in_sizes, int n_in,
                              void* d_out, int out_size, void* d_ws, size_t ws_size,
                              hipStream_t stream) {
  const void* x       = d_in[0];
  const void* theta_w = d_in[1];
  const void* theta_b = d_in[2];
  const void* phi_w   = d_in[3];
  const void* phi_b   = d_in[4];
  const void* g_w     = d_in[5];
  const void* g_b     = d_in[6];
  const void* W_w     = d_in[7];
  const void* W_b     = d_in[8];
  const void* gamma   = d_in[9];
  const void* beta    = d_in[10];

  char* wsb = (char*)d_ws;
  // round-3 layout exactly:
  //   [0, 16.78M)      xT -> ybuf
  //   [16.78M, 25.17M) theta -> W_y first half
  //   [25.17M, 33.55M) scratch (phi_c then g_c) -> W_y second half
  //   [33.55M, 35.65M) phi   [b][m][ci]
  //   [35.65M, 37.75M) gg    [b][ci][m]
  //   [37.75M+)        stats (512 f32), flag
  short* xT      = (short*)(wsb + 0);
  short* ybuf    = (short*)(wsb + 0);
  short* theta   = (short*)(wsb + 16777216);
  short* W_y     = (short*)(wsb + 16777216);
  short* scratch = (short*)(wsb + 25165824);
  short* phi     = (short*)(wsb + 33554432);
  short* gg      = (short*)(wsb + 35651584);
  float* stats   = (float*)(wsb + 37748736);
  int*   flag    = (int*)  (wsb + 37750784);

  dim3 blk(256);
  dim3 cgrid(64, 8);
  dim3 tgrid(64, 4, 8);

  hipMemsetAsync(stats, 0, 2048, stream);
  sniff_kernel<<<1, blk, 0, stream>>>((const unsigned short*)x, flag);
  transpose_x<<<tgrid, blk, 0, stream>>>(x, xT, flag);
  conv_t_k<<<cgrid, blk, 0, stream>>>(xT, theta_w, theta_b, theta, flag);
  conv_t_k<<<cgrid, blk, 0, stream>>>(xT, phi_w, phi_b, scratch, flag);
  pool_phi_kernel<<<4096, blk, 0, stream>>>(scratch, phi);
  conv_n_k<128, 256><<<cgrid, blk, 0, stream>>>(xT, g_w, g_b, scratch, flag);
  pool_g_kernel<<<4096, blk, 0, stream>>>(scratch, gg);
  attn_kernel<<<cgrid, blk, 0, stream>>>(theta, phi, gg, ybuf);
  convW_k<<<cgrid, blk, 0, stream>>>(ybuf, W_w, W_b, W_y, stats, flag);
  bn_apply4<<<8192, blk, 0, stream>>>(W_y, x, stats, gamma, beta, d_out, flag);
}